// Round 15
// baseline (211.964 us; speedup 1.0000x reference)
//
#include <hip/hip_runtime.h>
#include <hip/hip_fp16.h>
#include <cmath>

#define NN 50000
#define NE 800000
#define NPB 32
#define NBKT 196       // ceil(50000/256)
#define BKT_SHIFT 8    // 256 nodes per bucket
#define BKT_NODES 256
#define BKT_CAP 6144   // fixed region per bucket (mean ~4082, sigma ~64)
#define CHUNK 4096
#define NCH 196        // ceil(800000/4096)

using f16x8 = __attribute__((ext_vector_type(8))) _Float16;
using f32x4 = __attribute__((ext_vector_type(4))) float;

__device__ __forceinline__ float sigmoidf_(float x) {
    return 1.0f / (1.0f + __expf(-x));
}
__device__ __forceinline__ float tanhf_(float x) {
    float t = __expf(-2.0f * fabsf(x));
    float r = (1.0f - t) / (1.0f + t);
    return copysignf(r, x);
}

// decode 4 fp16 (uint2) -> accumulate into a[0..3]
__device__ __forceinline__ void accR(uint2 v, float* a) {
    float2 f;
    f = __half22float2(*(__half2*)&v.x); a[0] += f.x; a[1] += f.y;
    f = __half22float2(*(__half2*)&v.y); a[2] += f.x; a[3] += f.y;
}
__device__ __forceinline__ void accRm(uint2 v, float m, float* a) {
    float2 f;
    f = __half22float2(*(__half2*)&v.x); a[0] = fmaf(f.x, m, a[0]); a[1] = fmaf(f.y, m, a[1]);
    f = __half22float2(*(__half2*)&v.y); a[2] = fmaf(f.x, m, a[2]); a[3] = fmaf(f.y, m, a[3]);
}

// ---------------- prep: feat f32->f16 (row + col-blocked), WC, bias -----
// fqt layout: [cb][node][8 x uint2] (32 cols per block, 64 B/row, line-aligned)
__global__ __launch_bounds__(256) void prep_kernel(
    const float* __restrict__ feat, __half* __restrict__ feat_h,
    uint2* __restrict__ fqt,
    const float* __restrict__ Wih, const float* __restrict__ Whh,
    const float* __restrict__ b_ih, const float* __restrict__ b_hh,
    __half* __restrict__ WC, float* __restrict__ bsum,
    int* __restrict__ bcnt) {
    int i = blockIdx.x * blockDim.x + threadIdx.x;  // 0 .. 1,599,999

    {
        const float4 v = ((const float4*)feat)[i];
        __half2 lo = __floats2half2_rn(v.x, v.y);
        __half2 hi = __floats2half2_rn(v.z, v.w);
        ((__half2*)feat_h)[2 * i]     = lo;
        ((__half2*)feat_h)[2 * i + 1] = hi;
        int n  = i >> 5;          // node
        int f4 = i & 31;          // float4 within row
        int cb = f4 >> 3;         // col-block
        int w  = f4 & 7;          // uint2 within 64 B row
        uint2 u;
        u.x = *(unsigned*)&lo;
        u.y = *(unsigned*)&hi;
        fqt[(size_t)cb * NN * 8 + (size_t)n * 8 + w] = u;
    }
    // WC[g][0:128] = W_ih[g][:], WC[g][128:192] = W_hh[g][:]
    if (i < 256 * 128) {
        int g = i >> 7, k = i & 127;
        WC[(size_t)g * 192 + k] = __float2half(Wih[i]);
    }
    if (i < 256 * 64) {
        int g = i >> 6, k = i & 63;
        WC[(size_t)g * 192 + 128 + k] = __float2half(Whh[i]);
    }
    if (i < 256) bsum[i] = b_ih[i] + b_hh[i];
    if (i < 2 * NBKT) bcnt[i] = 0;
}

// ---------------- phase A: bin edges into fixed-stride bucket regions ---
__global__ __launch_bounds__(256) void bin_kernel(
    const int* __restrict__ src0, const int* __restrict__ dst0,
    const int* __restrict__ src1, const int* __restrict__ dst1,
    int* __restrict__ bcnt,   // [2*NBKT], zeroed by prep
    unsigned* __restrict__ binned0, unsigned* __restrict__ binned1) {
    __shared__ int cnt[NBKT];
    __shared__ int base[NBKT];
    __shared__ int cur[NBKT];
    __shared__ int sdst[CHUNK];

    int x  = blockIdx.x;             // 0 .. 2*NCH-1
    int et = x >= NCH;
    int c  = et ? x - NCH : x;
    const int* src = et ? src1 : src0;
    const int* dst = et ? dst1 : dst0;
    unsigned* binned = et ? binned1 : binned0;

    int start = c * CHUNK;
    int n = min(CHUNK, NE - start);
    int tid = threadIdx.x;

    if (tid < NBKT) { cnt[tid] = 0; cur[tid] = 0; }
    __syncthreads();
    for (int i = tid; i < n; i += 256) {
        int d = dst[start + i];
        sdst[i] = d;
        atomicAdd(&cnt[d >> BKT_SHIFT], 1);
    }
    __syncthreads();
    if (tid < NBKT && cnt[tid] > 0)
        base[tid] = atomicAdd(&bcnt[et * NBKT + tid], cnt[tid]);
    __syncthreads();
    for (int i = tid; i < n; i += 256) {
        int d = sdst[i];
        int b = d >> BKT_SHIFT;
        int r = atomicAdd(&cur[b], 1);
        binned[(size_t)b * BKT_CAP + base[b] + r] =
            ((unsigned)d << 16) | (unsigned)src[start + i];
    }
}

// ---------------- phase B: per-bucket CSR finalize + es scatter ---------
__global__ __launch_bounds__(256) void bucket_scatter_kernel(
    const unsigned* __restrict__ binned0, const unsigned* __restrict__ binned1,
    const int* __restrict__ bcnt,
    int* __restrict__ off0, int* __restrict__ off1,
    int* __restrict__ deg0, int* __restrict__ deg1,
    unsigned short* __restrict__ es0, unsigned short* __restrict__ es1) {
    __shared__ int lcnt[BKT_NODES];
    __shared__ int lbase[BKT_NODES];

    int g  = blockIdx.x;             // 0 .. 2*NBKT-1
    int et = g >= NBKT;
    int b  = et ? g - NBKT : g;
    const unsigned* binned = (et ? binned1 : binned0) + (size_t)b * BKT_CAP;
    int* off = et ? off1 : off0;
    int* deg = et ? deg1 : deg0;
    unsigned short* es = (et ? es1 : es0) + (size_t)b * BKT_CAP;

    int bn = bcnt[g];
    int node0 = b * BKT_NODES;
    int tid = threadIdx.x;

    lcnt[tid] = 0;
    __syncthreads();
    for (int i = tid; i < bn; i += 256) {
        unsigned u = binned[i];
        int d = (int)(u >> 16) - node0;
        atomicAdd(&lcnt[d], 1);
    }
    __syncthreads();
    int cntv = lcnt[tid];
    for (int d = 1; d < BKT_NODES; d <<= 1) {
        int v = (tid >= d) ? lcnt[tid - d] : 0;
        __syncthreads();
        lcnt[tid] += v;
        __syncthreads();
    }
    int excl = lcnt[tid] - cntv;
    lbase[tid] = excl;
    int gn = node0 + tid;
    if (gn < NN) { off[gn] = b * BKT_CAP + excl; deg[gn] = cntv; }
    __syncthreads();
    for (int i = tid; i < bn; i += 256) {
        unsigned u = binned[i];
        int d = (int)(u >> 16) - node0;
        int r = atomicAdd(&lbase[d], 1);
        es[r] = (unsigned short)(u & 0xffffu);
    }
}

// ---------------- gather pass: 32 cols, 3.2 MB table (L2-resident) ------
// wave = 1 node; 8 lanes/row (uint2), 8 rows per load instruction, x2
// unroll = 16 edges in flight. One dispatch per col-block cb -> the whole
// chip reads only this 3.2 MB table during the dispatch.
__global__ __launch_bounds__(256) void gather_pass_kernel(
    const uint2* __restrict__ fqt,   // this pass's table: [node][8] uint2
    const unsigned short* __restrict__ es0, const int* __restrict__ off0, const int* __restrict__ deg0,
    const unsigned short* __restrict__ es1, const int* __restrict__ off1, const int* __restrict__ deg1,
    unsigned long long* __restrict__ rstu, int cb) {
    int wid  = (blockIdx.x * blockDim.x + threadIdx.x) >> 6;
    int lane = threadIdx.x & 63;
    if (wid >= NN) return;
    int sub = lane >> 3;    // 0..7: edge slot within the octet
    int c   = lane & 7;     // uint2 col within the 64 B row

    float a0[4] = {0.f, 0.f, 0.f, 0.f};
    float a1[4] = {0.f, 0.f, 0.f, 0.f};

    int d0 = deg0[wid], o0 = off0[wid];
    int e = 0;
    for (; e + 16 <= d0; e += 16) {
        int sa = __builtin_nontemporal_load(&es0[o0 + e + sub]);
        int sb = __builtin_nontemporal_load(&es0[o0 + e + 8 + sub]);
        uint2 va = fqt[(size_t)sa * 8 + c];
        uint2 vb = fqt[(size_t)sb * 8 + c];
        accR(va, a0);
        accR(vb, a0);
    }
    if (e < d0) {
        int last = d0 - 1;
#pragma unroll
        for (int j = 0; j < 2; j++) {
            int ee = e + 8 * j + sub;
            int s = __builtin_nontemporal_load(&es0[o0 + min(ee, last)]);
            uint2 v = fqt[(size_t)s * 8 + c];
            accRm(v, (ee < d0) ? 1.f : 0.f, a0);
        }
    }

    int d1 = deg1[wid], o1 = off1[wid];
    e = 0;
    for (; e + 16 <= d1; e += 16) {
        int sa = __builtin_nontemporal_load(&es1[o1 + e + sub]);
        int sb = __builtin_nontemporal_load(&es1[o1 + e + 8 + sub]);
        uint2 va = fqt[(size_t)sa * 8 + c];
        uint2 vb = fqt[(size_t)sb * 8 + c];
        accR(va, a1);
        accR(vb, a1);
    }
    if (e < d1) {
        int last = d1 - 1;
#pragma unroll
        for (int j = 0; j < 2; j++) {
            int ee = e + 8 * j + sub;
            int s = __builtin_nontemporal_load(&es1[o1 + min(ee, last)]);
            uint2 v = fqt[(size_t)s * 8 + c];
            accRm(v, (ee < d1) ? 1.f : 0.f, a1);
        }
    }

    // reduce across the 8 edge slots (lane bits 3,4,5)
#pragma unroll
    for (int k = 0; k < 4; k++) {
        a0[k] += __shfl_xor(a0[k], 8, 64);
        a0[k] += __shfl_xor(a0[k], 16, 64);
        a0[k] += __shfl_xor(a0[k], 32, 64);
        a1[k] += __shfl_xor(a1[k], 8, 64);
        a1[k] += __shfl_xor(a1[k], 16, 64);
        a1[k] += __shfl_xor(a1[k], 32, 64);
    }

    if (lane < 8) {   // sub==0, c=lane: write this pass's 4-half slice
        float inv0 = 1.0f / fmaxf((float)d0, 1.0f);
        float inv1 = 1.0f / fmaxf((float)d1, 1.0f);
        float na = fmaxf((float)((d0 > 0) + (d1 > 0)), 1.0f);
        float v0 = (a0[0] * inv0 + a1[0] * inv1) / na;
        float v1 = (a0[1] * inv0 + a1[1] * inv1) / na;
        float v2 = (a0[2] * inv0 + a1[2] * inv1) / na;
        float v3 = (a0[3] * inv0 + a1[3] * inv1) / na;
        __half2 h01 = __floats2half2_rn(v0, v1);
        __half2 h23 = __floats2half2_rn(v2, v3);
        unsigned long long o = ((unsigned long long)(*(unsigned*)&h23) << 32)
                             | (unsigned long long)(*(unsigned*)&h01);
        __builtin_nontemporal_store(o, &rstu[(size_t)wid * 32 + cb * 8 + lane]);
    }
}

// ---------------- node kernel: MFMA gates GEMM + LSTM epilogue ----------
__global__ __launch_bounds__(256) void node_kernel(
    const __half* __restrict__ feat_h,
    const __half* __restrict__ rst_h,
    const __half* __restrict__ WC, const float* __restrict__ bsum,
    float* __restrict__ out) {
    __shared__ __half xs[32 * 200];

    int t  = threadIdx.x;
    int nb = blockIdx.x * NPB;
    int lane = t & 63;
    int w    = t >> 6;
    int col  = lane & 15;   // A-row / C-col / B-col
    int g4   = lane >> 4;   // k-group

    f16x8 bfr[4][6];
    float bias[4];
#pragma unroll
    for (int ct = 0; ct < 4; ct++) {
        int gate = ct * 64 + w * 16 + col;
        bias[ct] = bsum[gate];
#pragma unroll
        for (int ks = 0; ks < 6; ks++)
            bfr[ct][ks] = *(const f16x8*)(WC + (size_t)gate * 192 + ks * 32 + g4 * 8);
    }

    const uint4* feat4 = (const uint4*)feat_h;
    const uint4* rst4  = (const uint4*)rst_h;
#pragma unroll
    for (int j = 0; j < 2; j++) {
        int e = t + j * 256;
        int n = e >> 4, q = e & 15;
        int gn = nb + n;
        uint4 v = make_uint4(0, 0, 0, 0);
        if (gn < NN) v = feat4[(size_t)gn * 16 + q];
        *(uint4*)(&xs[n * 200 + q * 8]) = v;
    }
    {
        int n = t >> 3, q = t & 7;
        int gn = nb + n;
        uint4 v = make_uint4(0, 0, 0, 0);
        if (gn < NN) v = rst4[(size_t)gn * 16 + q];
        *(uint4*)(&xs[n * 200 + 128 + q * 8]) = v;
    }
    __syncthreads();

    f32x4 acc[2][4];
#pragma unroll
    for (int rt = 0; rt < 2; rt++)
#pragma unroll
        for (int ct = 0; ct < 4; ct++)
            acc[rt][ct] = (f32x4){bias[ct], bias[ct], bias[ct], bias[ct]};

#pragma unroll
    for (int ks = 0; ks < 6; ks++) {
        f16x8 a0 = *(const f16x8*)(&xs[(col) * 200 + ks * 32 + g4 * 8]);
        f16x8 a1 = *(const f16x8*)(&xs[(16 + col) * 200 + ks * 32 + g4 * 8]);
#pragma unroll
        for (int ct = 0; ct < 4; ct++) {
            acc[0][ct] = __builtin_amdgcn_mfma_f32_16x16x32_f16(a0, bfr[ct][ks], acc[0][ct], 0, 0, 0);
            acc[1][ct] = __builtin_amdgcn_mfma_f32_16x16x32_f16(a1, bfr[ct][ks], acc[1][ct], 0, 0, 0);
        }
    }

    int m = w * 16 + col;
#pragma unroll
    for (int rt = 0; rt < 2; rt++) {
#pragma unroll
        for (int r = 0; r < 4; r++) {
            int nl = rt * 16 + g4 * 4 + r;
            int gn = nb + nl;
            if (gn >= NN) continue;
            float iv = sigmoidf_(acc[rt][0][r]);
            float fv = sigmoidf_(acc[rt][1][r]);
            float gv = tanhf_(acc[rt][2][r]);
            float ov = sigmoidf_(acc[rt][3][r]);
            float R  = __half2float(rst_h[(size_t)gn * 128 + 64 + m]);
            float c1 = fv * R + iv * gv;
            float h1 = ov * tanhf_(c1);
            out[(size_t)gn * 128 + m]      = h1;
            out[(size_t)gn * 128 + 64 + m] = c1;
        }
    }
}

extern "C" void kernel_launch(void* const* d_in, const int* in_sizes, int n_in,
                              void* d_out, int out_size, void* d_ws, size_t ws_size,
                              hipStream_t stream) {
    const float* feat = (const float*)d_in[0];
    const int*   src0 = (const int*)d_in[1];
    const int*   dst0 = (const int*)d_in[2];
    const int*   src1 = (const int*)d_in[3];
    const int*   dst1 = (const int*)d_in[4];
    const float* W_ih = (const float*)d_in[5];
    const float* W_hh = (const float*)d_in[6];
    const float* b_ih = (const float*)d_in[7];
    const float* b_hh = (const float*)d_in[8];
    float* out = (float*)d_out;

    // workspace layout (16B-aligned pieces)
    char* p = (char*)d_ws;
    int* bcnt = (int*)p;            p += 2 * NBKT * 4;   // zeroed by prep
    int* off0 = (int*)p;            p += NN * 4;
    int* off1 = (int*)p;            p += NN * 4;
    int* deg0 = (int*)p;            p += NN * 4;
    int* deg1 = (int*)p;            p += NN * 4;
    unsigned* binned0 = (unsigned*)p; p += (size_t)NBKT * BKT_CAP * 4;  // 4.8 MB
    unsigned* binned1 = (unsigned*)p; p += (size_t)NBKT * BKT_CAP * 4;  // 4.8 MB
    unsigned short* es0 = (unsigned short*)p; p += (size_t)NBKT * BKT_CAP * 2;
    unsigned short* es1 = (unsigned short*)p; p += (size_t)NBKT * BKT_CAP * 2;
    __half* feat_h = (__half*)p;    p += (size_t)NN * 128 * 2;    // 12.8 MB row-major
    uint2*  fqt    = (uint2*)p;     p += (size_t)NN * 32 * 8;     // 12.8 MB col-blocked
    __half* rst_h  = (__half*)p;    p += (size_t)NN * 128 * 2;    // 12.8 MB
    __half* WC     = (__half*)p;    p += (size_t)256 * 192 * 2;
    float*  bsum   = (float*)p;     p += 256 * 4;

    int blocksP = (NN * 128 / 4 + 255) / 256;  // 6250
    prep_kernel<<<blocksP, 256, 0, stream>>>(feat, feat_h, fqt,
                                             W_ih, W_hh, b_ih, b_hh,
                                             WC, bsum, bcnt);

    bin_kernel<<<2 * NCH, 256, 0, stream>>>(src0, dst0, src1, dst1, bcnt,
                                            binned0, binned1);

    bucket_scatter_kernel<<<2 * NBKT, 256, 0, stream>>>(binned0, binned1, bcnt,
                                                        off0, off1, deg0, deg1,
                                                        es0, es1);

    int blocksG = (NN * 64 + 255) / 256;  // 12500 (one wave per node)
    for (int cb = 0; cb < 4; cb++) {
        gather_pass_kernel<<<blocksG, 256, 0, stream>>>(
            fqt + (size_t)cb * NN * 8,
            es0, off0, deg0, es1, off1, deg1,
            (unsigned long long*)rst_h, cb);
    }

    int blocksN = (NN + NPB - 1) / NPB;   // 1563
    node_kernel<<<blocksN, 256, 0, stream>>>(feat_h, rst_h, WC, bsum, out);
}

// Round 16
// 138.966 us; speedup vs baseline: 1.5253x; 1.5253x over previous
//
#include <hip/hip_runtime.h>
#include <hip/hip_fp16.h>
#include <cmath>

#define NN 50000
#define NE 800000
#define NPB 32
#define NBKT 196       // ceil(50000/256)
#define BKT_SHIFT 8    // 256 nodes per bucket
#define BKT_NODES 256
#define BKT_CAP 6144   // fixed region per bucket (mean ~4082, sigma ~64)
#define CHUNK 4096
#define NCH 196        // ceil(800000/4096)

using f16x8 = __attribute__((ext_vector_type(8))) _Float16;
using f32x4 = __attribute__((ext_vector_type(4))) float;

__device__ __forceinline__ float sigmoidf_(float x) {
    return 1.0f / (1.0f + __expf(-x));
}
__device__ __forceinline__ float tanhf_(float x) {
    float t = __expf(-2.0f * fabsf(x));
    float r = (1.0f - t) / (1.0f + t);
    return copysignf(r, x);
}

// ---------------- prep: feat f32->f16, WC fp16, bias, zero bcnt ---------
__global__ __launch_bounds__(256) void prep_kernel(
    const float* __restrict__ feat, __half* __restrict__ feat_h,
    const float* __restrict__ Wih, const float* __restrict__ Whh,
    const float* __restrict__ b_ih, const float* __restrict__ b_hh,
    __half* __restrict__ WC, float* __restrict__ bsum,
    int* __restrict__ bcnt) {
    int i = blockIdx.x * blockDim.x + threadIdx.x;  // 0 .. 1,599,999

    {
        const float4 v = ((const float4*)feat)[i];
        __half2 lo = __floats2half2_rn(v.x, v.y);
        __half2 hi = __floats2half2_rn(v.z, v.w);
        ((__half2*)feat_h)[2 * i]     = lo;
        ((__half2*)feat_h)[2 * i + 1] = hi;
    }
    // WC[g][0:128] = W_ih[g][:], WC[g][128:192] = W_hh[g][:]
    if (i < 256 * 128) {
        int g = i >> 7, k = i & 127;
        WC[(size_t)g * 192 + k] = __float2half(Wih[i]);
    }
    if (i < 256 * 64) {
        int g = i >> 6, k = i & 63;
        WC[(size_t)g * 192 + 128 + k] = __float2half(Whh[i]);
    }
    if (i < 256) bsum[i] = b_ih[i] + b_hh[i];
    if (i < 2 * NBKT) bcnt[i] = 0;
}

// ---------------- phase A: bin edges into fixed-stride bucket regions ---
// binned entry = (dst << 16) | src. Region for bucket b: [b*BKT_CAP, ...).
__global__ __launch_bounds__(256) void bin_kernel(
    const int* __restrict__ src0, const int* __restrict__ dst0,
    const int* __restrict__ src1, const int* __restrict__ dst1,
    int* __restrict__ bcnt,   // [2*NBKT], zeroed by prep
    unsigned* __restrict__ binned0, unsigned* __restrict__ binned1) {
    __shared__ int cnt[NBKT];
    __shared__ int base[NBKT];
    __shared__ int cur[NBKT];
    __shared__ int sdst[CHUNK];

    int x  = blockIdx.x;             // 0 .. 2*NCH-1
    int et = x >= NCH;
    int c  = et ? x - NCH : x;
    const int* src = et ? src1 : src0;
    const int* dst = et ? dst1 : dst0;
    unsigned* binned = et ? binned1 : binned0;

    int start = c * CHUNK;
    int n = min(CHUNK, NE - start);
    int tid = threadIdx.x;

    if (tid < NBKT) { cnt[tid] = 0; cur[tid] = 0; }
    __syncthreads();
    for (int i = tid; i < n; i += 256) {
        int d = dst[start + i];
        sdst[i] = d;
        atomicAdd(&cnt[d >> BKT_SHIFT], 1);
    }
    __syncthreads();
    if (tid < NBKT && cnt[tid] > 0)
        base[tid] = atomicAdd(&bcnt[et * NBKT + tid], cnt[tid]);
    __syncthreads();
    for (int i = tid; i < n; i += 256) {
        int d = sdst[i];
        int b = d >> BKT_SHIFT;
        int r = atomicAdd(&cur[b], 1);
        binned[(size_t)b * BKT_CAP + base[b] + r] =
            ((unsigned)d << 16) | (unsigned)src[start + i];
    }
}

// ---------------- phase B: per-bucket CSR finalize + es scatter ---------
// writes deg[] and off[] (off points into the bucket's fixed es region).
__global__ __launch_bounds__(256) void bucket_scatter_kernel(
    const unsigned* __restrict__ binned0, const unsigned* __restrict__ binned1,
    const int* __restrict__ bcnt,
    int* __restrict__ off0, int* __restrict__ off1,
    int* __restrict__ deg0, int* __restrict__ deg1,
    unsigned short* __restrict__ es0, unsigned short* __restrict__ es1) {
    __shared__ int lcnt[BKT_NODES];
    __shared__ int lbase[BKT_NODES];

    int g  = blockIdx.x;             // 0 .. 2*NBKT-1
    int et = g >= NBKT;
    int b  = et ? g - NBKT : g;
    const unsigned* binned = (et ? binned1 : binned0) + (size_t)b * BKT_CAP;
    int* off = et ? off1 : off0;
    int* deg = et ? deg1 : deg0;
    unsigned short* es = (et ? es1 : es0) + (size_t)b * BKT_CAP;

    int bn = bcnt[g];
    int node0 = b * BKT_NODES;
    int tid = threadIdx.x;

    lcnt[tid] = 0;
    __syncthreads();
    for (int i = tid; i < bn; i += 256) {
        unsigned u = binned[i];
        int d = (int)(u >> 16) - node0;
        atomicAdd(&lcnt[d], 1);
    }
    __syncthreads();
    int cntv = lcnt[tid];             // per-node count
    // inclusive Hillis-Steele scan, 1 element/thread
    for (int d = 1; d < BKT_NODES; d <<= 1) {
        int v = (tid >= d) ? lcnt[tid - d] : 0;
        __syncthreads();
        lcnt[tid] += v;
        __syncthreads();
    }
    int excl = lcnt[tid] - cntv;
    lbase[tid] = excl;
    int gn = node0 + tid;
    if (gn < NN) { off[gn] = b * BKT_CAP + excl; deg[gn] = cntv; }
    __syncthreads();
    for (int i = tid; i < bn; i += 256) {
        unsigned u = binned[i];
        int d = (int)(u >> 16) - node0;
        int r = atomicAdd(&lbase[d], 1);
        es[r] = (unsigned short)(u & 0xffffu);
    }
}

// ---------------- gather: wave per node, 2 rows/instr, 8 rows in flight -
// lane = (hf, c): hf = which row of the pair, c = uint2 col (4 halves).
__global__ __launch_bounds__(256) void gather_kernel(
    const uint2* __restrict__ featu,   // feat_h as uint2: 32 per 128-half row
    const unsigned short* __restrict__ es0, const int* __restrict__ off0, const int* __restrict__ deg0,
    const unsigned short* __restrict__ es1, const int* __restrict__ off1, const int* __restrict__ deg1,
    uint2* __restrict__ rstu) {
    int wid  = (blockIdx.x * blockDim.x + threadIdx.x) >> 6;
    int lane = threadIdx.x & 63;
    if (wid >= NN) return;
    int hf = lane >> 5;     // 0/1: which edge of the pair
    int c  = lane & 31;     // uint2 column

    float a0[4] = {0.f, 0.f, 0.f, 0.f};
    float a1[4] = {0.f, 0.f, 0.f, 0.f};

    int d0 = deg0[wid], o0 = off0[wid];
    int e = 0;
    for (; e + 8 <= d0; e += 8) {
        int s0 = es0[o0 + e + 0 + hf];
        int s1 = es0[o0 + e + 2 + hf];
        int s2 = es0[o0 + e + 4 + hf];
        int s3 = es0[o0 + e + 6 + hf];
        uint2 v0 = featu[(size_t)s0 * 32 + c];
        uint2 v1 = featu[(size_t)s1 * 32 + c];
        uint2 v2 = featu[(size_t)s2 * 32 + c];
        uint2 v3 = featu[(size_t)s3 * 32 + c];
        {
            float2 f;
            f = __half22float2(*(__half2*)&v0.x); a0[0] += f.x; a0[1] += f.y;
            f = __half22float2(*(__half2*)&v0.y); a0[2] += f.x; a0[3] += f.y;
            f = __half22float2(*(__half2*)&v1.x); a0[0] += f.x; a0[1] += f.y;
            f = __half22float2(*(__half2*)&v1.y); a0[2] += f.x; a0[3] += f.y;
            f = __half22float2(*(__half2*)&v2.x); a0[0] += f.x; a0[1] += f.y;
            f = __half22float2(*(__half2*)&v2.y); a0[2] += f.x; a0[3] += f.y;
            f = __half22float2(*(__half2*)&v3.x); a0[0] += f.x; a0[1] += f.y;
            f = __half22float2(*(__half2*)&v3.y); a0[2] += f.x; a0[3] += f.y;
        }
    }
    if (e < d0) {
        int last = d0 - 1;
#pragma unroll
        for (int j = 0; j < 4; j++) {
            int ee = e + 2 * j + hf;
            int s = es0[o0 + min(ee, last)];
            uint2 v = featu[(size_t)s * 32 + c];
            float m = (ee < d0) ? 1.f : 0.f;
            float2 f;
            f = __half22float2(*(__half2*)&v.x); a0[0] = fmaf(f.x, m, a0[0]); a0[1] = fmaf(f.y, m, a0[1]);
            f = __half22float2(*(__half2*)&v.y); a0[2] = fmaf(f.x, m, a0[2]); a0[3] = fmaf(f.y, m, a0[3]);
        }
    }

    int d1 = deg1[wid], o1 = off1[wid];
    e = 0;
    for (; e + 8 <= d1; e += 8) {
        int s0 = es1[o1 + e + 0 + hf];
        int s1 = es1[o1 + e + 2 + hf];
        int s2 = es1[o1 + e + 4 + hf];
        int s3 = es1[o1 + e + 6 + hf];
        uint2 v0 = featu[(size_t)s0 * 32 + c];
        uint2 v1 = featu[(size_t)s1 * 32 + c];
        uint2 v2 = featu[(size_t)s2 * 32 + c];
        uint2 v3 = featu[(size_t)s3 * 32 + c];
        {
            float2 f;
            f = __half22float2(*(__half2*)&v0.x); a1[0] += f.x; a1[1] += f.y;
            f = __half22float2(*(__half2*)&v0.y); a1[2] += f.x; a1[3] += f.y;
            f = __half22float2(*(__half2*)&v1.x); a1[0] += f.x; a1[1] += f.y;
            f = __half22float2(*(__half2*)&v1.y); a1[2] += f.x; a1[3] += f.y;
            f = __half22float2(*(__half2*)&v2.x); a1[0] += f.x; a1[1] += f.y;
            f = __half22float2(*(__half2*)&v2.y); a1[2] += f.x; a1[3] += f.y;
            f = __half22float2(*(__half2*)&v3.x); a1[0] += f.x; a1[1] += f.y;
            f = __half22float2(*(__half2*)&v3.y); a1[2] += f.x; a1[3] += f.y;
        }
    }
    if (e < d1) {
        int last = d1 - 1;
#pragma unroll
        for (int j = 0; j < 4; j++) {
            int ee = e + 2 * j + hf;
            int s = es1[o1 + min(ee, last)];
            uint2 v = featu[(size_t)s * 32 + c];
            float m = (ee < d1) ? 1.f : 0.f;
            float2 f;
            f = __half22float2(*(__half2*)&v.x); a1[0] = fmaf(f.x, m, a1[0]); a1[1] = fmaf(f.y, m, a1[1]);
            f = __half22float2(*(__half2*)&v.y); a1[2] = fmaf(f.x, m, a1[2]); a1[3] = fmaf(f.y, m, a1[3]);
        }
    }

    // combine the pair halves (lane ^ 32)
#pragma unroll
    for (int k = 0; k < 4; k++) {
        a0[k] += __shfl_xor(a0[k], 32, 64);
        a1[k] += __shfl_xor(a1[k], 32, 64);
    }

    if (hf == 0) {
        float inv0 = 1.0f / fmaxf((float)d0, 1.0f);
        float inv1 = 1.0f / fmaxf((float)d1, 1.0f);
        float na = fmaxf((float)((d0 > 0) + (d1 > 0)), 1.0f);
        float r0 = (a0[0] * inv0 + a1[0] * inv1) / na;
        float r1 = (a0[1] * inv0 + a1[1] * inv1) / na;
        float r2 = (a0[2] * inv0 + a1[2] * inv1) / na;
        float r3 = (a0[3] * inv0 + a1[3] * inv1) / na;
        __half2 h01 = __floats2half2_rn(r0, r1);
        __half2 h23 = __floats2half2_rn(r2, r3);
        uint2 o;
        o.x = *(unsigned*)&h01;
        o.y = *(unsigned*)&h23;
        rstu[(size_t)wid * 32 + c] = o;
    }
}

// ---------------- node kernel: MFMA gates GEMM + LSTM epilogue ----------
__global__ __launch_bounds__(256) void node_kernel(
    const __half* __restrict__ feat_h,
    const __half* __restrict__ rst_h,
    const __half* __restrict__ WC, const float* __restrict__ bsum,
    float* __restrict__ out) {
    __shared__ __half xs[32 * 200];

    int t  = threadIdx.x;
    int nb = blockIdx.x * NPB;
    int lane = t & 63;
    int w    = t >> 6;
    int col  = lane & 15;   // A-row / C-col / B-col
    int g4   = lane >> 4;   // k-group

    f16x8 bfr[4][6];
    float bias[4];
#pragma unroll
    for (int ct = 0; ct < 4; ct++) {
        int gate = ct * 64 + w * 16 + col;
        bias[ct] = bsum[gate];
#pragma unroll
        for (int ks = 0; ks < 6; ks++)
            bfr[ct][ks] = *(const f16x8*)(WC + (size_t)gate * 192 + ks * 32 + g4 * 8);
    }

    const uint4* feat4 = (const uint4*)feat_h;
    const uint4* rst4  = (const uint4*)rst_h;
#pragma unroll
    for (int j = 0; j < 2; j++) {
        int e = t + j * 256;
        int n = e >> 4, q = e & 15;
        int gn = nb + n;
        uint4 v = make_uint4(0, 0, 0, 0);
        if (gn < NN) v = feat4[(size_t)gn * 16 + q];
        *(uint4*)(&xs[n * 200 + q * 8]) = v;
    }
    {
        int n = t >> 3, q = t & 7;
        int gn = nb + n;
        uint4 v = make_uint4(0, 0, 0, 0);
        if (gn < NN) v = rst4[(size_t)gn * 16 + q];
        *(uint4*)(&xs[n * 200 + 128 + q * 8]) = v;
    }
    __syncthreads();

    f32x4 acc[2][4];
#pragma unroll
    for (int rt = 0; rt < 2; rt++)
#pragma unroll
        for (int ct = 0; ct < 4; ct++)
            acc[rt][ct] = (f32x4){bias[ct], bias[ct], bias[ct], bias[ct]};

#pragma unroll
    for (int ks = 0; ks < 6; ks++) {
        f16x8 a0 = *(const f16x8*)(&xs[(col) * 200 + ks * 32 + g4 * 8]);
        f16x8 a1 = *(const f16x8*)(&xs[(16 + col) * 200 + ks * 32 + g4 * 8]);
#pragma unroll
        for (int ct = 0; ct < 4; ct++) {
            acc[0][ct] = __builtin_amdgcn_mfma_f32_16x16x32_f16(a0, bfr[ct][ks], acc[0][ct], 0, 0, 0);
            acc[1][ct] = __builtin_amdgcn_mfma_f32_16x16x32_f16(a1, bfr[ct][ks], acc[1][ct], 0, 0, 0);
        }
    }

    int m = w * 16 + col;
#pragma unroll
    for (int rt = 0; rt < 2; rt++) {
#pragma unroll
        for (int r = 0; r < 4; r++) {
            int nl = rt * 16 + g4 * 4 + r;
            int gn = nb + nl;
            if (gn >= NN) continue;
            float iv = sigmoidf_(acc[rt][0][r]);
            float fv = sigmoidf_(acc[rt][1][r]);
            float gv = tanhf_(acc[rt][2][r]);
            float ov = sigmoidf_(acc[rt][3][r]);
            float R  = __half2float(rst_h[(size_t)gn * 128 + 64 + m]);
            float c1 = fv * R + iv * gv;
            float h1 = ov * tanhf_(c1);
            out[(size_t)gn * 128 + m]      = h1;
            out[(size_t)gn * 128 + 64 + m] = c1;
        }
    }
}

extern "C" void kernel_launch(void* const* d_in, const int* in_sizes, int n_in,
                              void* d_out, int out_size, void* d_ws, size_t ws_size,
                              hipStream_t stream) {
    const float* feat = (const float*)d_in[0];
    const int*   src0 = (const int*)d_in[1];
    const int*   dst0 = (const int*)d_in[2];
    const int*   src1 = (const int*)d_in[3];
    const int*   dst1 = (const int*)d_in[4];
    const float* W_ih = (const float*)d_in[5];
    const float* W_hh = (const float*)d_in[6];
    const float* b_ih = (const float*)d_in[7];
    const float* b_hh = (const float*)d_in[8];
    float* out = (float*)d_out;

    // workspace layout (16B-aligned pieces)
    char* p = (char*)d_ws;
    int* bcnt = (int*)p;            p += 2 * NBKT * 4;   // zeroed by prep
    int* off0 = (int*)p;            p += NN * 4;
    int* off1 = (int*)p;            p += NN * 4;
    int* deg0 = (int*)p;            p += NN * 4;
    int* deg1 = (int*)p;            p += NN * 4;
    unsigned* binned0 = (unsigned*)p; p += (size_t)NBKT * BKT_CAP * 4;  // 4.8 MB
    unsigned* binned1 = (unsigned*)p; p += (size_t)NBKT * BKT_CAP * 4;  // 4.8 MB
    unsigned short* es0 = (unsigned short*)p; p += (size_t)NBKT * BKT_CAP * 2;
    unsigned short* es1 = (unsigned short*)p; p += (size_t)NBKT * BKT_CAP * 2;
    __half* feat_h = (__half*)p;    p += (size_t)NN * 128 * 2;
    __half* rst_h  = (__half*)p;    p += (size_t)NN * 128 * 2;
    __half* WC     = (__half*)p;    p += (size_t)256 * 192 * 2;
    float*  bsum   = (float*)p;     p += 256 * 4;

    int blocksP = (NN * 128 / 4 + 255) / 256;  // 6250
    prep_kernel<<<blocksP, 256, 0, stream>>>(feat, feat_h, W_ih, W_hh, b_ih, b_hh,
                                             WC, bsum, bcnt);

    bin_kernel<<<2 * NCH, 256, 0, stream>>>(src0, dst0, src1, dst1, bcnt,
                                            binned0, binned1);

    bucket_scatter_kernel<<<2 * NBKT, 256, 0, stream>>>(binned0, binned1, bcnt,
                                                        off0, off1, deg0, deg1,
                                                        es0, es1);

    int blocksG = (NN * 64 + 255) / 256;  // 12500 (one wave per node)
    gather_kernel<<<blocksG, 256, 0, stream>>>((const uint2*)feat_h,
                                               es0, off0, deg0, es1, off1, deg1,
                                               (uint2*)rst_h);

    int blocksN = (NN + NPB - 1) / NPB;   // 1563
    node_kernel<<<blocksN, 256, 0, stream>>>(feat_h, rst_h, WC, bsum, out);
}